// Round 1
// baseline (3414.730 us; speedup 1.0000x reference)
//
#include <hip/hip_runtime.h>

#define NN 20000
#define NE 640000

__device__ __forceinline__ float silu_f(float x) {
    return x / (1.0f + __expf(-x));
}

// ---------------------------------------------------------------------------
// Kernel A: per-node precompute.
// y0 = x0 @ W1_0 / sqrt(32)                      -> yAll[n][0:32]
// y1[n,v,m] = sum_u x1[n,u,m] W1_1[u,v] /sqrt32  -> yAll[n][32 + v*3 + m]
// y2[n,v,m] = sum_u x2[n,u,m] W1_2[u,v] /sqrt32  -> yAll[n][128 + v*5 + m]
// sc[h,n,w] = sum_{u,t} x0[n,u] na[n,t] scW[h,u,t,w] / sqrt(128)
// block = 256 threads = 8 nodes x 32 channels
// ---------------------------------------------------------------------------
__global__ __launch_bounds__(256) void node_pre(
    const float* __restrict__ x,
    const float* __restrict__ na,
    const float* __restrict__ W10,
    const float* __restrict__ W11,
    const float* __restrict__ W12,
    const float* __restrict__ scW,
    float* __restrict__ yAll,
    float* __restrict__ sc)
{
    __shared__ float xs[8][288];
    __shared__ float nas[8][4];
    __shared__ float w10[1024];
    __shared__ float w11[1024];
    __shared__ float w12[1024];
    const int tid = threadIdx.x;
    const int nodeBase = blockIdx.x * 8;

    for (int i = tid; i < 1024; i += 256) { w10[i] = W10[i]; w11[i] = W11[i]; w12[i] = W12[i]; }
    for (int i = tid; i < 8 * 288; i += 256) {
        int nl = i / 288, c = i % 288;
        int n = nodeBase + nl;
        xs[nl][c] = (n < NN) ? x[(long)n * 288 + c] : 0.f;
    }
    if (tid < 32) {
        int nl = tid >> 2, t = tid & 3;
        int n = nodeBase + nl;
        nas[nl][t] = (n < NN) ? na[n * 4 + t] : 0.f;
    }
    __syncthreads();

    const int nl = tid >> 5, v = tid & 31;
    const int n = nodeBase + nl;
    if (n >= NN) return;

    const float inv_mul = 0.17677669529663687f;  // 1/sqrt(32)
    float* yrow = yAll + (long)n * 288;

    // y0
    {
        float a = 0.f;
        #pragma unroll
        for (int u = 0; u < 32; ++u) a += xs[nl][u] * w10[u * 32 + v];
        yrow[v] = a * inv_mul;
    }
    // y1
    {
        float a0 = 0.f, a1 = 0.f, a2 = 0.f;
        #pragma unroll
        for (int u = 0; u < 32; ++u) {
            float wv = w11[u * 32 + v];
            a0 += xs[nl][32 + u * 3 + 0] * wv;
            a1 += xs[nl][32 + u * 3 + 1] * wv;
            a2 += xs[nl][32 + u * 3 + 2] * wv;
        }
        yrow[32 + v * 3 + 0] = a0 * inv_mul;
        yrow[32 + v * 3 + 1] = a1 * inv_mul;
        yrow[32 + v * 3 + 2] = a2 * inv_mul;
    }
    // y2
    {
        float a[5] = {0.f, 0.f, 0.f, 0.f, 0.f};
        #pragma unroll
        for (int u = 0; u < 32; ++u) {
            float wv = w12[u * 32 + v];
            #pragma unroll
            for (int m = 0; m < 5; ++m) a[m] += xs[nl][128 + u * 5 + m] * wv;
        }
        #pragma unroll
        for (int m = 0; m < 5; ++m) yrow[128 + v * 5 + m] = a[m] * inv_mul;
    }
    // sc — scW read straight from global: lane v reads 32 consecutive floats
    // (coalesced 128B line), 48KB total weight stays hot in L1/L2.
    const float inv_sc = 0.08838834764831845f;  // 1/sqrt(128)
    #pragma unroll
    for (int hh = 0; hh < 3; ++hh) {
        float acc = 0.f;
        for (int u = 0; u < 32; ++u) {
            float t = 0.f;
            #pragma unroll
            for (int tt = 0; tt < 4; ++tt)
                t += nas[nl][tt] * scW[((hh * 32 + u) * 4 + tt) * 32 + v];
            acc += xs[nl][u] * t;
        }
        sc[((long)hh * NN + n) * 32 + v] = acc * inv_sc;
    }
}

// ---------------------------------------------------------------------------
// Kernel B: fused edge MLP + message + atomic scatter. One thread per edge
// (grid-stride). Weights transposed in LDS so the 64-long dot reads
// consecutive floats (ds_read_b128-friendly, wave-uniform broadcast).
// ---------------------------------------------------------------------------
__global__ __launch_bounds__(256) void edge_kernel(
    const float* __restrict__ ee,
    const float* __restrict__ ea,
    const int*   __restrict__ ei,
    const float* __restrict__ Wm0,
    const float* __restrict__ Wm1,
    const float* __restrict__ yAll,
    float* __restrict__ mid)
{
    __shared__ float wm0t[64][8];    // wm0t[i][k] = Wm0[k*64 + i]
    __shared__ float wm1t[96][64];   // wm1t[j][i] = Wm1[i*96 + j]
    const int tid = threadIdx.x;
    for (int idx = tid; idx < 512; idx += 256) {
        int k = idx / 64, i = idx % 64;
        wm0t[i][k] = Wm0[idx];
    }
    for (int idx = tid; idx < 6144; idx += 256) {
        int i = idx / 96, j = idx % 96;
        wm1t[j][i] = Wm1[idx];
    }
    __syncthreads();

    const float inv_sqrt8 = 0.35355339059327373f;  // 1/sqrt(NB)
    const float inv8      = 0.125f;                // 1/sqrt(HID)
    const float invAVG    = 0.17677669529663687f;  // 1/sqrt(32)
    const float inv_sqrt3 = 0.5773502691896258f;
    const float inv_sqrt5 = 0.4472135954999579f;

    for (int e = blockIdx.x * blockDim.x + tid; e < NE; e += gridDim.x * blockDim.x) {
        const int s = ei[e];
        const int d = ei[NE + e];

        float emb[8];
        #pragma unroll
        for (int k = 0; k < 8; ++k) emb[k] = ee[(long)e * 8 + k];

        float h[64];
        #pragma unroll
        for (int i = 0; i < 64; ++i) {
            float t = 0.f;
            #pragma unroll
            for (int k = 0; k < 8; ++k) t += emb[k] * wm0t[i][k];
            h[i] = silu_f(t * inv_sqrt8);
        }

        float eav[9];
        #pragma unroll
        for (int k = 0; k < 9; ++k) eav[k] = ea[(long)e * 9 + k];

        const float* yb = yAll + (long)s * 288;
        float* midRow = mid + (long)d * 96;

        // m0
        for (int u = 0; u < 32; ++u) {
            float wj = 0.f;
            #pragma unroll
            for (int i = 0; i < 64; ++i) wj += h[i] * wm1t[u][i];
            float m = wj * inv8 * (yb[u] * eav[0]) * invAVG;
            unsafeAtomicAdd(&midRow[u], m);
        }
        // m1
        for (int u = 0; u < 32; ++u) {
            float wj = 0.f;
            #pragma unroll
            for (int i = 0; i < 64; ++i) wj += h[i] * wm1t[32 + u][i];
            float dotv = yb[32 + u * 3 + 0] * eav[1]
                       + yb[32 + u * 3 + 1] * eav[2]
                       + yb[32 + u * 3 + 2] * eav[3];
            float m = wj * inv8 * (dotv * inv_sqrt3) * invAVG;
            unsafeAtomicAdd(&midRow[32 + u], m);
        }
        // m2
        for (int u = 0; u < 32; ++u) {
            float wj = 0.f;
            #pragma unroll
            for (int i = 0; i < 64; ++i) wj += h[i] * wm1t[64 + u][i];
            float dotv = 0.f;
            #pragma unroll
            for (int m5 = 0; m5 < 5; ++m5) dotv += yb[128 + u * 5 + m5] * eav[4 + m5];
            float m = wj * inv8 * (dotv * inv_sqrt5) * invAVG;
            unsafeAtomicAdd(&midRow[64 + u], m);
        }
    }
}

// ---------------------------------------------------------------------------
// Kernel C: output GEMV + sc + silu. block = 8 nodes x 32 channels.
// ---------------------------------------------------------------------------
__global__ __launch_bounds__(256) void node_out(
    const float* __restrict__ mid,
    const float* __restrict__ sc,
    const float* __restrict__ L0,
    const float* __restrict__ L1,
    const float* __restrict__ L2,
    float* __restrict__ out)
{
    __shared__ float l0[32 * 32];
    __shared__ float l1[64 * 32];
    __shared__ float l2[96 * 32];
    __shared__ float ms[8][96];
    const int tid = threadIdx.x;
    const int nodeBase = blockIdx.x * 8;

    for (int i = tid; i < 1024; i += 256) l0[i] = L0[i];
    for (int i = tid; i < 2048; i += 256) l1[i] = L1[i];
    for (int i = tid; i < 3072; i += 256) l2[i] = L2[i];
    for (int i = tid; i < 768; i += 256) {
        int nl = i / 96, c = i % 96;
        int n = nodeBase + nl;
        ms[nl][c] = (n < NN) ? mid[(long)n * 96 + c] : 0.f;
    }
    __syncthreads();

    const int nl = tid >> 5, w = tid & 31;
    const int n = nodeBase + nl;
    if (n >= NN) return;

    float a0 = 0.f, a1 = 0.f, a2 = 0.f;
    #pragma unroll
    for (int u = 0; u < 32; ++u) {
        float m = ms[nl][u];
        a0 += m * l0[u * 32 + w];
        a1 += m * l1[u * 32 + w];
        a2 += m * l2[u * 32 + w];
    }
    #pragma unroll
    for (int u = 32; u < 64; ++u) {
        float m = ms[nl][u];
        a1 += m * l1[u * 32 + w];
        a2 += m * l2[u * 32 + w];
    }
    #pragma unroll
    for (int u = 64; u < 96; ++u) a2 += ms[nl][u] * l2[u * 32 + w];

    const float is32 = 0.17677669529663687f;   // 1/sqrt(32)
    const float is64 = 0.125f;                 // 1/sqrt(64)
    const float is96 = 0.10206207261596575f;   // 1/sqrt(96)
    const long base = (long)n * 32 + w;
    out[base]                   = silu_f(a0 * is32 + sc[base]);
    out[(long)NN * 32 + base]   = silu_f(a1 * is64 + sc[(long)NN * 32 + base]);
    out[(long)2 * NN * 32 + base] = silu_f(a2 * is96 + sc[(long)2 * NN * 32 + base]);
}

extern "C" void kernel_launch(void* const* d_in, const int* in_sizes, int n_in,
                              void* d_out, int out_size, void* d_ws, size_t ws_size,
                              hipStream_t stream)
{
    const float* x   = (const float*)d_in[0];
    const float* na  = (const float*)d_in[1];
    const float* ee  = (const float*)d_in[2];
    const float* ea  = (const float*)d_in[3];
    const int*   ei  = (const int*)d_in[4];
    const float* W10 = (const float*)d_in[5];
    const float* W11 = (const float*)d_in[6];
    const float* W12 = (const float*)d_in[7];
    const float* Wm0 = (const float*)d_in[8];
    const float* Wm1 = (const float*)d_in[9];
    const float* L0  = (const float*)d_in[10];
    const float* L1  = (const float*)d_in[11];
    const float* L2  = (const float*)d_in[12];
    const float* scW = (const float*)d_in[13];
    float* out = (float*)d_out;

    float* yAll = (float*)d_ws;                    // NN*288 floats
    float* sc   = yAll + (size_t)NN * 288;         // 3*NN*32 floats
    float* mid  = sc + (size_t)3 * NN * 32;        // NN*96 floats

    hipMemsetAsync(mid, 0, (size_t)NN * 96 * sizeof(float), stream);
    node_pre<<<(NN + 7) / 8, 256, 0, stream>>>(x, na, W10, W11, W12, scW, yAll, sc);
    edge_kernel<<<1280, 256, 0, stream>>>(ee, ea, ei, Wm0, Wm1, yAll, mid);
    node_out<<<(NN + 7) / 8, 256, 0, stream>>>(mid, sc, L0, L1, L2, out);
}

// Round 2
// 663.191 us; speedup vs baseline: 5.1489x; 5.1489x over previous
//
#include <hip/hip_runtime.h>

#define NN 20000
#define NE 640000
#define ECH 128000   // edge chunk (NE/5), w buffer reused per chunk

__device__ __forceinline__ float silu_f(float x) {
    return x / (1.0f + __expf(-x));
}

// ---------------------------------------------------------------------------
// Kernel A: per-node precompute (unchanged from R1 — not a bottleneck).
// ---------------------------------------------------------------------------
__global__ __launch_bounds__(256) void node_pre(
    const float* __restrict__ x,
    const float* __restrict__ na,
    const float* __restrict__ W10,
    const float* __restrict__ W11,
    const float* __restrict__ W12,
    const float* __restrict__ scW,
    float* __restrict__ yAll,
    float* __restrict__ sc)
{
    __shared__ float xs[8][288];
    __shared__ float nas[8][4];
    __shared__ float w10[1024];
    __shared__ float w11[1024];
    __shared__ float w12[1024];
    const int tid = threadIdx.x;
    const int nodeBase = blockIdx.x * 8;

    for (int i = tid; i < 1024; i += 256) { w10[i] = W10[i]; w11[i] = W11[i]; w12[i] = W12[i]; }
    for (int i = tid; i < 8 * 288; i += 256) {
        int nl = i / 288, c = i % 288;
        int n = nodeBase + nl;
        xs[nl][c] = (n < NN) ? x[(long)n * 288 + c] : 0.f;
    }
    if (tid < 32) {
        int nl = tid >> 2, t = tid & 3;
        int n = nodeBase + nl;
        nas[nl][t] = (n < NN) ? na[n * 4 + t] : 0.f;
    }
    __syncthreads();

    const int nl = tid >> 5, v = tid & 31;
    const int n = nodeBase + nl;
    if (n >= NN) return;

    const float inv_mul = 0.17677669529663687f;  // 1/sqrt(32)
    float* yrow = yAll + (long)n * 288;

    {
        float a = 0.f;
        #pragma unroll
        for (int u = 0; u < 32; ++u) a += xs[nl][u] * w10[u * 32 + v];
        yrow[v] = a * inv_mul;
    }
    {
        float a0 = 0.f, a1 = 0.f, a2 = 0.f;
        #pragma unroll
        for (int u = 0; u < 32; ++u) {
            float wv = w11[u * 32 + v];
            a0 += xs[nl][32 + u * 3 + 0] * wv;
            a1 += xs[nl][32 + u * 3 + 1] * wv;
            a2 += xs[nl][32 + u * 3 + 2] * wv;
        }
        yrow[32 + v * 3 + 0] = a0 * inv_mul;
        yrow[32 + v * 3 + 1] = a1 * inv_mul;
        yrow[32 + v * 3 + 2] = a2 * inv_mul;
    }
    {
        float a[5] = {0.f, 0.f, 0.f, 0.f, 0.f};
        #pragma unroll
        for (int u = 0; u < 32; ++u) {
            float wv = w12[u * 32 + v];
            #pragma unroll
            for (int m = 0; m < 5; ++m) a[m] += xs[nl][128 + u * 5 + m] * wv;
        }
        #pragma unroll
        for (int m = 0; m < 5; ++m) yrow[128 + v * 5 + m] = a[m] * inv_mul;
    }
    const float inv_sc = 0.08838834764831845f;  // 1/sqrt(128)
    #pragma unroll
    for (int hh = 0; hh < 3; ++hh) {
        float acc = 0.f;
        for (int u = 0; u < 32; ++u) {
            float t = 0.f;
            #pragma unroll
            for (int tt = 0; tt < 4; ++tt)
                t += nas[nl][tt] * scW[((hh * 32 + u) * 4 + tt) * 32 + v];
            acc += xs[nl][u] * t;
        }
        sc[((long)hh * NN + n) * 32 + v] = acc * inv_sc;
    }
}

// ---------------------------------------------------------------------------
// Kernel B1: w = silu(ee@Wm0/sqrt8) @ Wm1 / sqrt64 for a chunk of edges.
// Tile = 64 edges per block. Register blocking: thread (g=tid>>5, u=tid&31)
// computes edges g*8..g*8+7 x channels {u, u+32, u+64}. LDS strides padded
// to 68 floats: wm1t reads 4-way conflict (1.58x), h reads 2-way (free),
// 16B-aligned for ds_read_b128.
// ---------------------------------------------------------------------------
__global__ __launch_bounds__(256) void edge_w(
    const float* __restrict__ ee,
    const float* __restrict__ Wm0,
    const float* __restrict__ Wm1,
    float* __restrict__ w,
    int ebase)
{
    __shared__ float wm0s[512];        // [k*64 + i]
    __shared__ float wm1t[96 * 68];    // [c*68 + k]
    __shared__ float ees[64 * 8];      // [e*8 + k]
    __shared__ float hs[64 * 68];      // [e*68 + k]
    const int tid = threadIdx.x;
    const int eb = ebase + blockIdx.x * 64;   // global edge base of tile
    const int leb = blockIdx.x * 64;          // chunk-local edge base

    for (int i = tid; i < 512; i += 256) wm0s[i] = Wm0[i];
    for (int i = tid; i < 6144; i += 256) {
        int k = i / 96, c = i % 96;
        wm1t[c * 68 + k] = Wm1[i];
    }
    for (int i = tid; i < 512; i += 256) ees[i] = ee[(long)eb * 8 + i];
    __syncthreads();

    // phase 1: h[e][i] = silu((ee[e] . Wm0[:,i]) / sqrt8)
    {
        const float inv_sqrt8 = 0.35355339059327373f;
        const int e = tid >> 2, i0 = (tid & 3) * 16;
        float emb[8];
        #pragma unroll
        for (int k = 0; k < 8; ++k) emb[k] = ees[e * 8 + k];
        #pragma unroll
        for (int i = 0; i < 16; ++i) {
            float t = 0.f;
            #pragma unroll
            for (int k = 0; k < 8; ++k) t += emb[k] * wm0s[k * 64 + i0 + i];
            hs[e * 68 + i0 + i] = silu_f(t * inv_sqrt8);
        }
    }
    __syncthreads();

    // phase 2: w[e][c] = h[e] . Wm1[:,c] * 0.125
    const int u = tid & 31, g = tid >> 5;
    float acc[3][8];
    #pragma unroll
    for (int cc = 0; cc < 3; ++cc)
        #pragma unroll
        for (int j = 0; j < 8; ++j) acc[cc][j] = 0.f;

    #pragma unroll
    for (int k = 0; k < 64; k += 4) {
        float4 wv0 = *(const float4*)&wm1t[u * 68 + k];
        float4 wv1 = *(const float4*)&wm1t[(u + 32) * 68 + k];
        float4 wv2 = *(const float4*)&wm1t[(u + 64) * 68 + k];
        #pragma unroll
        for (int j = 0; j < 8; ++j) {
            float4 hv = *(const float4*)&hs[(g * 8 + j) * 68 + k];
            acc[0][j] += hv.x * wv0.x + hv.y * wv0.y + hv.z * wv0.z + hv.w * wv0.w;
            acc[1][j] += hv.x * wv1.x + hv.y * wv1.y + hv.z * wv1.z + hv.w * wv1.w;
            acc[2][j] += hv.x * wv2.x + hv.y * wv2.y + hv.z * wv2.z + hv.w * wv2.w;
        }
    }
    #pragma unroll
    for (int j = 0; j < 8; ++j) {
        long row = (long)(leb + g * 8 + j) * 96;
        #pragma unroll
        for (int cc = 0; cc < 3; ++cc)
            w[row + cc * 32 + u] = acc[cc][j] * 0.125f;   // fold 1/sqrt(HID)
    }
}

// ---------------------------------------------------------------------------
// Kernel B2: message + atomic scatter. One thread per (edge, u). Block =
// 8 edges x 32 lanes. All loads coalesced or intra-group broadcast; 3
// device-scope fp32 atomics per thread.
// ---------------------------------------------------------------------------
__global__ __launch_bounds__(256) void edge_scatter(
    const float* __restrict__ w,
    const float* __restrict__ ea,
    const int*   __restrict__ ei,
    const float* __restrict__ yAll,
    float* __restrict__ mid,
    int ebase)
{
    const int tid = threadIdx.x;
    const int le = blockIdx.x * 8 + (tid >> 5);   // chunk-local edge
    const int e = ebase + le;
    const int u = tid & 31;

    const float invAVG    = 0.17677669529663687f;  // 1/sqrt(32)
    const float inv_sqrt3 = 0.5773502691896258f;
    const float inv_sqrt5 = 0.4472135954999579f;

    const int s = ei[e];
    const int d = ei[NE + e];
    const float* yb  = yAll + (long)s * 288;
    const float* eav = ea + (long)e * 9;
    const float* wr  = w + (long)le * 96;

    float w0 = wr[u], w1 = wr[32 + u], w2 = wr[64 + u];

    float m0 = w0 * (yb[u] * eav[0]) * invAVG;

    float dot1 = yb[32 + u * 3 + 0] * eav[1]
               + yb[32 + u * 3 + 1] * eav[2]
               + yb[32 + u * 3 + 2] * eav[3];
    float m1 = w1 * dot1 * inv_sqrt3 * invAVG;

    float dot2 = 0.f;
    #pragma unroll
    for (int m = 0; m < 5; ++m) dot2 += yb[128 + u * 5 + m] * eav[4 + m];
    float m2 = w2 * dot2 * inv_sqrt5 * invAVG;

    float* midRow = mid + (long)d * 96;
    unsafeAtomicAdd(&midRow[u], m0);
    unsafeAtomicAdd(&midRow[32 + u], m1);
    unsafeAtomicAdd(&midRow[64 + u], m2);
}

// ---------------------------------------------------------------------------
// Kernel C: output GEMV + sc + silu (unchanged from R1).
// ---------------------------------------------------------------------------
__global__ __launch_bounds__(256) void node_out(
    const float* __restrict__ mid,
    const float* __restrict__ sc,
    const float* __restrict__ L0,
    const float* __restrict__ L1,
    const float* __restrict__ L2,
    float* __restrict__ out)
{
    __shared__ float l0[32 * 32];
    __shared__ float l1[64 * 32];
    __shared__ float l2[96 * 32];
    __shared__ float ms[8][96];
    const int tid = threadIdx.x;
    const int nodeBase = blockIdx.x * 8;

    for (int i = tid; i < 1024; i += 256) l0[i] = L0[i];
    for (int i = tid; i < 2048; i += 256) l1[i] = L1[i];
    for (int i = tid; i < 3072; i += 256) l2[i] = L2[i];
    for (int i = tid; i < 768; i += 256) {
        int nl = i / 96, c = i % 96;
        int n = nodeBase + nl;
        ms[nl][c] = (n < NN) ? mid[(long)n * 96 + c] : 0.f;
    }
    __syncthreads();

    const int nl = tid >> 5, wv = tid & 31;
    const int n = nodeBase + nl;
    if (n >= NN) return;

    float a0 = 0.f, a1 = 0.f, a2 = 0.f;
    #pragma unroll
    for (int u = 0; u < 32; ++u) {
        float m = ms[nl][u];
        a0 += m * l0[u * 32 + wv];
        a1 += m * l1[u * 32 + wv];
        a2 += m * l2[u * 32 + wv];
    }
    #pragma unroll
    for (int u = 32; u < 64; ++u) {
        float m = ms[nl][u];
        a1 += m * l1[u * 32 + wv];
        a2 += m * l2[u * 32 + wv];
    }
    #pragma unroll
    for (int u = 64; u < 96; ++u) a2 += ms[nl][u] * l2[u * 32 + wv];

    const float is32 = 0.17677669529663687f;
    const float is64 = 0.125f;
    const float is96 = 0.10206207261596575f;
    const long base = (long)n * 32 + wv;
    out[base]                     = silu_f(a0 * is32 + sc[base]);
    out[(long)NN * 32 + base]     = silu_f(a1 * is64 + sc[(long)NN * 32 + base]);
    out[(long)2 * NN * 32 + base] = silu_f(a2 * is96 + sc[(long)2 * NN * 32 + base]);
}

extern "C" void kernel_launch(void* const* d_in, const int* in_sizes, int n_in,
                              void* d_out, int out_size, void* d_ws, size_t ws_size,
                              hipStream_t stream)
{
    const float* x   = (const float*)d_in[0];
    const float* na  = (const float*)d_in[1];
    const float* ee  = (const float*)d_in[2];
    const float* ea  = (const float*)d_in[3];
    const int*   ei  = (const int*)d_in[4];
    const float* W10 = (const float*)d_in[5];
    const float* W11 = (const float*)d_in[6];
    const float* W12 = (const float*)d_in[7];
    const float* Wm0 = (const float*)d_in[8];
    const float* Wm1 = (const float*)d_in[9];
    const float* L0  = (const float*)d_in[10];
    const float* L1  = (const float*)d_in[11];
    const float* L2  = (const float*)d_in[12];
    const float* scW = (const float*)d_in[13];
    float* out = (float*)d_out;

    float* yAll = (float*)d_ws;                    // NN*288
    float* sc   = yAll + (size_t)NN * 288;         // 3*NN*32
    float* mid  = sc + (size_t)3 * NN * 32;        // NN*96
    float* wbuf = mid + (size_t)NN * 96;           // ECH*96 (reused per chunk)

    hipMemsetAsync(mid, 0, (size_t)NN * 96 * sizeof(float), stream);
    node_pre<<<(NN + 7) / 8, 256, 0, stream>>>(x, na, W10, W11, W12, scW, yAll, sc);

    for (int c = 0; c < NE / ECH; ++c) {
        int ebase = c * ECH;
        edge_w<<<ECH / 64, 256, 0, stream>>>(ee, Wm0, Wm1, wbuf, ebase);
        edge_scatter<<<ECH / 8, 256, 0, stream>>>(wbuf, ea, ei, yAll, mid, ebase);
    }

    node_out<<<(NN + 7) / 8, 256, 0, stream>>>(mid, sc, L0, L1, L2, out);
}